// Round 7
// baseline (2339.302 us; speedup 1.0000x reference)
//
#include <hip/hip_runtime.h>
#include <hip/hip_bf16.h>
#include <math.h>

#define N_PTS 131072
#define NSEG  8192
#define NKK   20
#define PRED  12
#define KP    192   // padded K: 2 rel + 40 dtp + 128 h + 22 zero
#define LPAD  136   // LDS row stride (elements) for conflict-free b128 reads

typedef __hip_bfloat16 bf16;
typedef __attribute__((ext_vector_type(8))) short short8;
typedef __attribute__((ext_vector_type(2))) short short2v;
typedef __attribute__((ext_vector_type(4))) float float4v;

__device__ __forceinline__ float b2f(bf16 x){ return __bfloat162float(x); }
__device__ __forceinline__ float b2fs(short s){
  unsigned int u = ((unsigned int)(unsigned short)s)<<16;
  return __uint_as_float(u);
}
__device__ __forceinline__ unsigned short f2bu(float f){
  bf16 h = __float2bfloat16(f);
  return *reinterpret_cast<unsigned short*>(&h);
}
__device__ __forceinline__ float sigm(float x){ return 1.0f/(1.0f+__expf(-x)); }
__device__ __forceinline__ float tanh_f(float x){
  x = fminf(15.f, fmaxf(-15.f, x));
  float e = __expf(2.f*x);
  return (e-1.f)/(e+1.f);
}
__device__ __forceinline__ float ldf(const void* p, long long i, bool bf){
  return bf ? __bfloat162float(((const bf16*)p)[i]) : ((const float*)p)[i];
}
__device__ __forceinline__ int ldseg(const void* p, long long i, bool i64){
  return i64 ? (int)(((const long long*)p)[i]) : ((const int*)p)[i];
}
__device__ __forceinline__ void stf(void* p, long long i, float v, bool bf){
  if(bf) ((bf16*)p)[i] = __float2bfloat16(v);
  else   ((float*)p)[i] = v;
}

// ---------- dtype probes: flags[0]=float-is-bf16, flags[1]=segids-int64, flags[2]=mask mode(0=i32,1=byte,2=i64)
__global__ void k_probe(const unsigned short* __restrict__ wx,
                        const int* __restrict__ seg,
                        const unsigned char* __restrict__ msk,
                        int* __restrict__ flags){
  int lane = threadIdx.x & 63;
  unsigned short h1 = wx[2*lane], h2 = wx[128+2*lane];
  int e1 = (h1>>7)&255, e2 = (h2>>7)&255;
  bool p1 = (e1>=100 && e1<=132), p2 = (e2>=100 && e2<=132);
  int cnt = __popcll(__ballot(p1)) + __popcll(__ballot(p2));
  int v = seg[65536+lane];
  int zc = __popcll(__ballot((lane&1) && v==0));
  bool nz1=false, nz2=false;
  for(int i=lane;i<4096;i+=64){
    unsigned char b = msk[i];
    if((i&3)!=0 && b) nz1=true;
    if((i&7)==4 && b) nz2=true;
  }
  unsigned long long b1 = __ballot(nz1), b2 = __ballot(nz2);
  if(lane==0){
    flags[0] = (cnt>=64) ? 1 : 0;
    flags[1] = (zc>=24) ? 1 : 0;
    flags[2] = b1 ? 1 : (b2 ? 0 : 2);
  }
}

__global__ void k_conv(const unsigned char* __restrict__ mraw, const int* __restrict__ flags,
                       unsigned char* __restrict__ mask){
  int i = blockIdx.x*256+threadIdx.x;
  if(i>=N_PTS) return;
  int mode = flags[2];
  unsigned char v;
  if(mode==1)      v = mraw[i]!=0;
  else if(mode==0) v = ((const int*)mraw)[i]!=0;
  else             v = ((const long long*)mraw)[i]!=0;
  mask[i]=v;
}

__global__ void k_segstart(const void* __restrict__ seg, const int* __restrict__ flags,
                           int* __restrict__ start){
  int s = blockIdx.x*256+threadIdx.x;
  if(s>NSEG) return;
  bool i64 = flags[1]!=0;
  int lo=0, hi=N_PTS;
  while(lo<hi){ int mid=(lo+hi)>>1; if(ldseg(seg,mid,i64)<s) lo=mid+1; else hi=mid; }
  start[s]=lo;
}

// ---------- fold weights.
// wTs: swizzled B operand for s2. Element (n,k), n=g*128+n':
//   ntg=n'/16, lm=n'%16, kc=k/32, lq=(k%32)/8, j=k%8
//   addr = ((g*8+ntg)*6 + kc)*512 + lq*128 + lm*8 + j   -> each (tile,chunk) is one contiguous 1KB
// wpoolT[128][128] bf16 (n-major), wxT2[512][128] bf16 (n-major), bias fp32[512]
__global__ void k_fold(const void* __restrict__ Wpos, const void* __restrict__ bpos,
                       const void* __restrict__ Wfld, const void* __restrict__ bfld,
                       const void* __restrict__ Wx,   const void* __restrict__ Wh,
                       const void* __restrict__ blstm, const int* __restrict__ flags,
                       short* __restrict__ wTs, float* __restrict__ bias,
                       short* __restrict__ wpoolT, const void* __restrict__ Wpool,
                       short* __restrict__ wxT2){
  int idx = blockIdx.x*256+threadIdx.x;
  bool bf = flags[0]!=0;
  if(idx < 512*KP){
    int n = idx/KP, k = idx - n*KP;
    float v;
    if(k<2){
      float a=0; for(int j=0;j<64;j++) a += ldf(Wpos,k*64+j,bf)*ldf(Wx,j*512+n,bf);
      v=a;
    } else if(k<42){
      int kk=k-2; float a=0; for(int j=0;j<64;j++) a += ldf(Wfld,kk*64+j,bf)*ldf(Wx,(64+j)*512+n,bf);
      v=a;
    } else if(k<170){
      v = ldf(Wh,(long long)(k-42)*512+n,bf);
    } else v = 0.f;
    int g = n>>7, np = n&127;
    int ntg = np>>4, lm = np&15;
    int kc = k>>5, lq = (k&31)>>3, j = k&7;
    long long addr = ((long long)((g*8+ntg)*6 + kc))*512 + lq*128 + lm*8 + j;
    ((bf16*)wTs)[addr] = __float2bfloat16(v);
  } else if(idx < 512*KP+512){
    int c = idx - 512*KP;
    float a=ldf(blstm,c,bf);
    for(int j=0;j<64;j++) a += ldf(bpos,j,bf)*ldf(Wx,j*512+c,bf) + ldf(bfld,j,bf)*ldf(Wx,(64+j)*512+c,bf);
    bias[c]=a;
  } else if(idx < 512*KP+512+128*128){
    int j = idx - (512*KP+512);
    int n = j>>7, k = j&127;
    ((bf16*)wpoolT)[j] = __float2bfloat16(ldf(Wpool,k*128+n,bf));
  } else if(idx < 512*KP+512+128*128+512*128){
    int j = idx - (512*KP+512+128*128);
    int n = j>>7, k = j&127;
    ((bf16*)wxT2)[j] = __float2bfloat16(ldf(Wx,(long long)(128+k)*512+n,bf));
  }
}

// ---------- init: build Apk[p][192], c=0, rel/pos fp32, al fp32, traj[0] ----------
__global__ void k_init(const void* __restrict__ sf, const void* __restrict__ lastpos,
                       const void* __restrict__ alpha0, const void* __restrict__ fd0,
                       const void* __restrict__ Wout, const void* __restrict__ bout,
                       const int* __restrict__ flags,
                       short* __restrict__ Apk, float* __restrict__ c,
                       float* __restrict__ rel, float* __restrict__ pos,
                       float* __restrict__ al, void* __restrict__ traj){
  int grp = threadIdx.x>>6, lane = threadIdx.x&63;
  int p = blockIdx.x*4+grp;
  bool bf = flags[0]!=0;
  bf16* Ap = (bf16*)Apk + (long long)p*KP;
  float h0 = ldf(sf,(long long)p*128+lane,bf);
  float h1 = ldf(sf,(long long)p*128+64+lane,bf);
  Ap[42+lane]      = __float2bfloat16(h0);
  Ap[42+64+lane]   = __float2bfloat16(h1);
  c[(long long)p*128+lane]=0.f; c[(long long)p*128+64+lane]=0.f;
  float o0 = h0*ldf(Wout,lane*2,bf)   + h1*ldf(Wout,(64+lane)*2,bf);
  float o1 = h0*ldf(Wout,lane*2+1,bf) + h1*ldf(Wout,(64+lane)*2+1,bf);
  for(int m=1;m<64;m<<=1){ o0 += __shfl_xor(o0,m); o1 += __shfl_xor(o1,m); }
  o0 += ldf(bout,0,bf); o1 += ldf(bout,1,bf);
  float a = 0.f;
  if(lane<NKK) a = ldf(alpha0,(long long)p*NKK+lane,bf);
  float s = a;
  for(int m=1;m<64;m<<=1) s += __shfl_xor(s,m);
  float aln = a/s;
  if(lane<NKK) al[(long long)p*NKK+lane] = aln;
  float alq = __shfl(aln, lane>>1);
  if(lane<2*NKK) Ap[2+lane] = __float2bfloat16(ldf(fd0,(long long)p*2*NKK+lane,bf)*alq);
  if(lane<22)    Ap[170+lane] = __float2bfloat16(0.f);
  if(lane==0){
    Ap[0]=__float2bfloat16(o0); Ap[1]=__float2bfloat16(o1);
    rel[p*2]=o0; rel[p*2+1]=o1;
    pos[p*2]   = ldf(lastpos,p*2,bf)  +o0;
    pos[p*2+1] = ldf(lastpos,p*2+1,bf)+o1;
    stf(traj, (long long)p*2,   o0, bf);
    stf(traj, (long long)p*2+1, o1, bf);
  }
}

// ---------- per-step FUSED s1: segmax -> pool -> contrib (all via LDS) ----------
// 256 blocks x 512 threads. Block owns 32 segments.
// Bit-exactness: phase A is pure fmax (reassociation-exact, finite inputs); phases B/C
// preserve per-accumulator MFMA chain order; no contractible scalar mul-add chains.
// s2/s3 are kept verbatim from the verified kernel (fp-contraction context preserved).
__launch_bounds__(512,2)
__global__ void s1_fused(const short* __restrict__ Apk, const int* __restrict__ start,
                         const short* __restrict__ wpoolT, const void* __restrict__ bpool,
                         const int* __restrict__ flags, const short* __restrict__ wxT2,
                         float* __restrict__ contrib){
  __shared__ short lsm[32*LPAD];
  __shared__ short lpool[32*LPAD];
  const int tid = threadIdx.x;
  const int S0  = blockIdx.x*32;

  // ---- phase A: segmax. one wave per segment, 4 passes.
  {
    const int t64 = tid&63;
    const int wg  = tid>>6;          // 0..7
    #pragma unroll
    for(int pass=0; pass<4; pass++){
      const int sgl = wg + pass*8;   // local seg 0..31
      const int s = S0 + sgl;
      const int a = start[s], b = start[s+1];
      float m0=-INFINITY, m1=-INFINITY;
      const short* bp0 = Apk + 42 + t64*2;   // dims t64*2, t64*2+1 ; 4B-aligned
      int i=a;
      for(; i+4<=b; i+=4){
        short2v v0 = *(const short2v*)(bp0 + (long long)(i  )*KP);
        short2v v1 = *(const short2v*)(bp0 + (long long)(i+1)*KP);
        short2v v2 = *(const short2v*)(bp0 + (long long)(i+2)*KP);
        short2v v3 = *(const short2v*)(bp0 + (long long)(i+3)*KP);
        m0 = fmaxf(fmaxf(fmaxf(m0,b2fs(v0[0])),fmaxf(b2fs(v1[0]),b2fs(v2[0]))),b2fs(v3[0]));
        m1 = fmaxf(fmaxf(fmaxf(m1,b2fs(v0[1])),fmaxf(b2fs(v1[1]),b2fs(v2[1]))),b2fs(v3[1]));
      }
      for(; i<b; i++){
        short2v v = *(const short2v*)(bp0 + (long long)i*KP);
        m0 = fmaxf(m0, b2fs(v[0]));
        m1 = fmaxf(m1, b2fs(v[1]));
      }
      if(a>=b){ m0=0.f; m1=0.f; }
      unsigned int pk = (((unsigned int)f2bu(m1))<<16) | (unsigned int)f2bu(m0);
      *(unsigned int*)(&lsm[sgl*LPAD + t64*2]) = pk;
    }
  }
  __syncthreads();

  const int w  = tid>>6, l = tid&63, lm = l&15, lq = l>>4;
  const bool bf = flags[0]!=0;

  // ---- phase B: pool MFMA (A from LDS lsm), result -> lpool (LDS)
  {
    float4v acc0=(float4v)(0.f), acc1=(float4v)(0.f);
    #pragma unroll
    for(int kc=0;kc<4;kc++){
      short8 b  = *(const short8*)(wpoolT + (long long)(w*16+lm)*128 + lq*8 + kc*32);
      short8 a0 = *(const short8*)(lsm + (0*16+lm)*LPAD + kc*32 + lq*8);
      short8 a1 = *(const short8*)(lsm + (1*16+lm)*LPAD + kc*32 + lq*8);
      acc0 = __builtin_amdgcn_mfma_f32_16x16x32_bf16(a0, b, acc0,0,0,0);
      acc1 = __builtin_amdgcn_mfma_f32_16x16x32_bf16(a1, b, acc1,0,0,0);
    }
    const int n = w*16+lm;
    float bv = ldf(bpool,n,bf);
    #pragma unroll
    for(int q=0;q<4;q++){
      int s0r = 0*16 + lq*4 + q;
      int s1r = 1*16 + lq*4 + q;
      lpool[s0r*LPAD+n] = (short)f2bu(fmaxf(acc0[q]+bv, 0.f));
      lpool[s1r*LPAD+n] = (short)f2bu(fmaxf(acc1[q]+bv, 0.f));
    }
  }
  __syncthreads();

  // ---- phase C: contrib MFMA (A from LDS lpool) -> global fp32 [seg][512]
  {
    float4v acc[2][4];
    #pragma unroll
    for(int mt=0;mt<2;mt++)
      #pragma unroll
      for(int j=0;j<4;j++) acc[mt][j] = (float4v)(0.f);
    #pragma unroll
    for(int kc=0;kc<4;kc++){
      short8 a0 = *(const short8*)(lpool + (0*16+lm)*LPAD + kc*32 + lq*8);
      short8 a1 = *(const short8*)(lpool + (1*16+lm)*LPAD + kc*32 + lq*8);
      short8 bb[4];
      #pragma unroll
      for(int j=0;j<4;j++)
        bb[j] = *(const short8*)(wxT2 + (long long)(w*64+j*16+lm)*128 + lq*8 + kc*32);
      #pragma unroll
      for(int j=0;j<4;j++){
        acc[0][j] = __builtin_amdgcn_mfma_f32_16x16x32_bf16(a0, bb[j], acc[0][j],0,0,0);
        acc[1][j] = __builtin_amdgcn_mfma_f32_16x16x32_bf16(a1, bb[j], acc[1][j],0,0,0);
      }
    }
    #pragma unroll
    for(int mt=0;mt<2;mt++)
      #pragma unroll
      for(int j=0;j<4;j++)
        #pragma unroll
        for(int q=0;q<4;q++){
          int s = S0 + mt*16 + lq*4 + q;
          contrib[(long long)s*512 + w*64 + j*16 + lm] = acc[mt][j][q];
        }
  }
}

// ---------- per-step: MFMA gates GEMM (M=32/block, N=512, K=192) + fused LSTM pointwise ----------
// VERBATIM from the verified 2417.9us kernel (codegen context preserved for bit-exactness).
__launch_bounds__(256,3)
__global__ void s2_mfma(short* __restrict__ Apk, float* __restrict__ c_st,
                        const short* __restrict__ wTs, const float* __restrict__ bias,
                        const float* __restrict__ contrib,
                        const void* __restrict__ segids, const int* __restrict__ flags,
                        const unsigned char* __restrict__ mask){
  const int tid = threadIdx.x;
  const int w   = tid>>6;
  const int l   = tid&63;
  const int lm  = l&15;
  const int lq  = l>>4;
  const int P0  = blockIdx.x*32;
  const bool i64 = flags[1]!=0;

  // hoisted epilogue metadata: 8 points per thread
  uchar4 mk[2];
  int sg[2][4];
  #pragma unroll
  for(int mt=0;mt<2;mt++){
    int pb = P0 + mt*16 + lq*4;
    mk[mt] = *(const uchar4*)(mask + pb);
    #pragma unroll
    for(int q=0;q<4;q++) sg[mt][q] = ldseg(segids, pb+q, i64);
  }

  float4v acc[2][4][2];   // [m-tile][gate][j] -> 64 VGPRs
  #pragma unroll
  for(int mt=0;mt<2;mt++)
    #pragma unroll
    for(int g=0;g<4;g++)
      #pragma unroll
      for(int j=0;j<2;j++) acc[mt][g][j] = (float4v)(0.f);

  const short* ap = Apk + (long long)(P0+lm)*KP + lq*8;
  const short* bp = wTs + lq*128 + lm*8;   // fragment (g,j,kc) at + ((g*8 + w*2 + j)*6 + kc)*512

  #pragma unroll
  for(int kc=0;kc<6;kc++){
    short8 a0 = *(const short8*)(ap + 0*16*KP + kc*32);
    short8 a1 = *(const short8*)(ap + 1*16*KP + kc*32);
    short8 b[4][2];
    #pragma unroll
    for(int g=0;g<4;g++)
      #pragma unroll
      for(int j=0;j<2;j++)
        b[g][j] = *(const short8*)(bp + ((long long)((g*8 + w*2 + j)*6 + kc))*512);
    #pragma unroll
    for(int g=0;g<4;g++)
      #pragma unroll
      for(int j=0;j<2;j++){
        acc[0][g][j] = __builtin_amdgcn_mfma_f32_16x16x32_bf16(a0, b[g][j], acc[0][g][j],0,0,0);
        acc[1][g][j] = __builtin_amdgcn_mfma_f32_16x16x32_bf16(a1, b[g][j], acc[1][g][j],0,0,0);
      }
  }

  __syncthreads();   // all A reads (incl. h cols) complete before any h write below

  float bi[4][2];
  #pragma unroll
  for(int g=0;g<4;g++)
    #pragma unroll
    for(int j=0;j<2;j++)
      bi[g][j] = bias[g*128 + w*32 + j*16 + lm];

  #pragma unroll
  for(int mt=0;mt<2;mt++){
    #pragma unroll
    for(int q=0;q<4;q++){
      unsigned char mq = (q==0)?mk[mt].x:(q==1)?mk[mt].y:(q==2)?mk[mt].z:mk[mt].w;
      if(!mq) continue;
      int p = P0 + mt*16 + lq*4 + q;
      const float* cb = contrib + (long long)sg[mt][q]*512;
      float* crow = c_st + (long long)p*128;
      bf16* hrow = (bf16*)Apk + (long long)p*KP + 42;
      #pragma unroll
      for(int j=0;j<2;j++){
        int d = w*32 + j*16 + lm;
        float gi = acc[mt][0][j][q] + bi[0][j] + cb[      d];
        float gf = acc[mt][1][j][q] + bi[1][j] + cb[128 + d];
        float gg = acc[mt][2][j][q] + bi[2][j] + cb[256 + d];
        float go = acc[mt][3][j][q] + bi[3][j] + cb[384 + d];
        float co = crow[d];
        float cn = sigm(gf)*co + sigm(gi)*tanh_f(gg);
        float hn = sigm(go)*tanh_f(cn);
        crow[d] = cn;
        hrow[d] = __float2bfloat16(hn);
      }
    }
  }
}

// ---------- per-step epilogue: out head, rel/pos, alpha softmax, fields->dtp, traj ----------
// VERBATIM from the verified 2417.9us kernel.
__global__ void s3_post(const short* __restrict__ Apk_c, short* __restrict__ Apk,
                        float* __restrict__ rel, float* __restrict__ pos, float* __restrict__ al,
                        const void* __restrict__ Wout, const void* __restrict__ bout,
                        const void* __restrict__ fieldA, const void* __restrict__ trans,
                        const int* __restrict__ flags,
                        const unsigned char* __restrict__ mask, void* __restrict__ traj, int t){
  int grp = threadIdx.x>>6, lane = threadIdx.x&63;
  int p = blockIdx.x*4+grp;
  bool bf = flags[0]!=0;
  const bf16* hrow = (const bf16*)Apk_c + (long long)p*KP + 42;
  float h0 = b2f(hrow[lane]), h1 = b2f(hrow[64+lane]);
  float o0 = h0*ldf(Wout,lane*2,bf)   + h1*ldf(Wout,(64+lane)*2,bf);
  float o1 = h0*ldf(Wout,lane*2+1,bf) + h1*ldf(Wout,(64+lane)*2+1,bf);
  for(int m=1;m<64;m<<=1){ o0 += __shfl_xor(o0,m); o1 += __shfl_xor(o1,m); }
  o0 += ldf(bout,0,bf); o1 += ldf(bout,1,bf);
  bool msk = mask[p]!=0;
  float r0 = rel[p*2], r1 = rel[p*2+1];
  if(msk){ r0=o0; r1=o1; }
  float pn0 = pos[p*2]+r0, pn1 = pos[p*2+1]+r1;
  float a_l = (lane<NKK)? al[(long long)p*NKK+lane] : 0.f;
  float ad = -INFINITY;
  if(lane<NKK){
    float a2=0.f;
    #pragma unroll
    for(int i=0;i<NKK;i++) a2 += __shfl(a_l,i)*ldf(trans,i*NKK+lane,bf);
    ad = a2;
  }
  float mx = ad;
  for(int m=1;m<64;m<<=1) mx = fmaxf(mx, __shfl_xor(mx,m));
  float e = (lane<NKK)? __expf(ad-mx) : 0.f;
  float se = e;
  for(int m=1;m<64;m<<=1) se += __shfl_xor(se,m);
  float alp = e/se;
  if(msk && lane<NKK) al[(long long)p*NKK+lane] = alp;
  float alq = __shfl(alp, lane>>1);
  if(msk && lane<2*NKK){
    int kk=lane>>1, ee=lane&1;
    float fp = pn0*ldf(fieldA,kk*4+ee,bf) + pn1*ldf(fieldA,kk*4+2+ee,bf);
    ((bf16*)Apk)[(long long)p*KP+2+lane] = __float2bfloat16(fp*alq);
  }
  if(lane==0){
    if(msk){
      ((bf16*)Apk)[(long long)p*KP+0] = __float2bfloat16(r0);
      ((bf16*)Apk)[(long long)p*KP+1] = __float2bfloat16(r1);
    }
    rel[p*2]=r0; rel[p*2+1]=r1;
    pos[p*2]=pn0; pos[p*2+1]=pn1;
    long long base = (long long)t*N_PTS*2 + (long long)p*2;
    stf(traj, base,   r0, bf);
    stf(traj, base+1, r1, bf);
  }
}

extern "C" void kernel_launch(void* const* d_in, const int* in_sizes, int n_in,
                              void* d_out, int out_size, void* d_ws, size_t ws_size,
                              hipStream_t stream){
  const void* sf      = d_in[0];
  const void* lastpos = d_in[1];
  const void* alpha0  = d_in[2];
  const void* fd0     = d_in[3];
  const void* Wpos    = d_in[4];
  const void* bpos    = d_in[5];
  const void* Wfld    = d_in[6];
  const void* bfld    = d_in[7];
  const void* Wpool   = d_in[8];
  const void* bpool   = d_in[9];
  const void* Wx      = d_in[10];
  const void* Wh      = d_in[11];
  const void* blstm   = d_in[12];
  const void* Wout    = d_in[13];
  const void* bout    = d_in[14];
  const void* fieldA  = d_in[15];
  const void* trans   = d_in[16];
  const void* segids  = d_in[17];
  const unsigned char* maskraw = (const unsigned char*)d_in[18];

  char* ws = (char*)d_ws;
  size_t o = 0;
  auto alc = [&](size_t b){ size_t r=o; o=(o+b+255)&~(size_t)255; return r; };
  short* Apk       = (short*)(ws+alc((size_t)N_PTS*KP*2));
  float* c_st      = (float*)(ws+alc((size_t)N_PTS*128*4));
  float* rel       = (float*)(ws+alc((size_t)N_PTS*2*4));
  float* pos       = (float*)(ws+alc((size_t)N_PTS*2*4));
  float* al        = (float*)(ws+alc((size_t)N_PTS*20*4));
  int*   segst     = (int*)  (ws+alc((size_t)(NSEG+1)*4));
  float* contrib   = (float*)(ws+alc((size_t)NSEG*512*4));
  short* wTs       = (short*)(ws+alc((size_t)512*KP*2));
  float* bias      = (float*)(ws+alc((size_t)512*4));
  short* wpoolT    = (short*)(ws+alc((size_t)128*128*2));
  short* wxT2      = (short*)(ws+alc((size_t)512*128*2));
  unsigned char* mask = (unsigned char*)(ws+alc((size_t)N_PTS));
  int*   flags     = (int*)  (ws+alc(64));

  k_probe<<<1,64,0,stream>>>((const unsigned short*)Wx, (const int*)segids, maskraw, flags);
  k_conv<<<512,256,0,stream>>>(maskraw, flags, mask);
  k_segstart<<<33,256,0,stream>>>(segids, flags, segst);
  k_fold<<<706,256,0,stream>>>(Wpos,bpos,Wfld,bfld,Wx,Wh,blstm,flags,wTs,bias,wpoolT,Wpool,wxT2);
  k_init<<<32768,256,0,stream>>>(sf,lastpos,alpha0,fd0,Wout,bout,flags,Apk,c_st,rel,pos,al,d_out);

  for(int t=1;t<PRED;t++){
    s1_fused<<<NSEG/32,512,0,stream>>>(Apk, segst, wpoolT, bpool, flags, wxT2, contrib);
    s2_mfma<<<N_PTS/32,256,0,stream>>>(Apk, c_st, wTs, bias, contrib, segids, flags, mask);
    s3_post<<<N_PTS/4,256,0,stream>>>(Apk, Apk, rel, pos, al, Wout, bout, fieldA, trans, flags, mask, d_out, t);
  }
}